// Round 1
// baseline (197.923 us; speedup 1.0000x reference)
//
#include <hip/hip_runtime.h>
#include <hip/hip_bf16.h>
#include <stdint.h>

#define B_    32
#define QLEN  1024
#define KSEQ  1024
#define DIM   128
#define SCALE 0.08838834764831845f   // 1/sqrt(128)

typedef __attribute__((ext_vector_type(8))) short  short8;
typedef __attribute__((ext_vector_type(4))) short  shortx4;
typedef __attribute__((ext_vector_type(4))) float  floatx4;

__device__ __forceinline__ unsigned short f2bf(float x) {
  union { float f; unsigned int u; } v; v.f = x;
  unsigned int r = v.u + 0x7FFF + ((v.u >> 16) & 1);   // round-to-nearest-even
  return (unsigned short)(r >> 16);
}

// ---------------- pre-pass: V [B][K][D] fp32  ->  VT [B][D][K] bf16 ----------------
__global__ __launch_bounds__(256) void vt_kernel(const float* __restrict__ V,
                                                 unsigned short* __restrict__ VT) {
  __shared__ float tile[32][33];
  const int b = blockIdx.z, k0 = blockIdx.y * 32, d0 = blockIdx.x * 32;
  const int tx = threadIdx.x, ty = threadIdx.y;
  const float* Vb = V + ((size_t)b * KSEQ + k0) * DIM + d0;
#pragma unroll
  for (int i = 0; i < 4; i++)
    tile[ty + 8 * i][tx] = Vb[(size_t)(ty + 8 * i) * DIM + tx];
  __syncthreads();
  unsigned short* VTb = VT + ((size_t)b * DIM + d0) * KSEQ + k0;
#pragma unroll
  for (int i = 0; i < 4; i++)
    VTb[(size_t)(ty + 8 * i) * KSEQ + tx] = f2bf(tile[tx][ty + 8 * i]);
}

// ---------------- main flash-attention kernel ----------------
// block = 256 threads = 4 waves; each wave owns 16 query rows; block owns 64.
// grid = (QLEN/64, B)
__global__ __launch_bounds__(256, 2) void attn_kernel(
    const float* __restrict__ Qg, const float* __restrict__ Kg,
    const unsigned short* __restrict__ VTg, const int* __restrict__ vlen,
    float* __restrict__ Og) {
  // K-tile: 32 keys x 128 bf16, stride 136 shorts (272B, 16B-aligned rows, 2-way banks)
  __shared__ short Kl[32][136];
  // VT-tile: 128 d x 32 keys bf16, stride 40 shorts (80B rows)
  __shared__ short Vl[128][40];
  // per-wave P tile: 16 q x 32 k bf16
  __shared__ short Pl[4][16][40];

  const int b    = blockIdx.y;
  const int q0   = blockIdx.x * 64;
  const int t    = threadIdx.x;
  const int wave = t >> 6, lane = t & 63, quad = lane >> 4, m = lane & 15;
  const int qw   = q0 + wave * 16;
  const int L    = vlen[b];
  const int ntiles = (L + 31) >> 5;

  // ---- load Q fragments (A-layout: row m = lane&15, k = quad*8 + j), bf16 ----
  short8 aq[4];
  {
    const float* qrow = Qg + ((size_t)b * QLEN + qw + m) * DIM;
#pragma unroll
    for (int c = 0; c < 4; c++) {
      floatx4 f0 = *(const floatx4*)(qrow + c * 32 + quad * 8);
      floatx4 f1 = *(const floatx4*)(qrow + c * 32 + quad * 8 + 4);
      short8 a;
      a[0] = (short)f2bf(f0[0]); a[1] = (short)f2bf(f0[1]);
      a[2] = (short)f2bf(f0[2]); a[3] = (short)f2bf(f0[3]);
      a[4] = (short)f2bf(f1[0]); a[5] = (short)f2bf(f1[1]);
      a[6] = (short)f2bf(f1[2]); a[7] = (short)f2bf(f1[3]);
      aq[c] = a;
    }
  }

  // ---- online-softmax state (per lane: 4 rows quad*4+r) ----
  float mrow[4], lrow[4];
  floatx4 oacc[8];
#pragma unroll
  for (int r = 0; r < 4; r++) { mrow[r] = -INFINITY; lrow[r] = 0.0f; }
#pragma unroll
  for (int d = 0; d < 8; d++) oacc[d] = (floatx4){0.f, 0.f, 0.f, 0.f};

  const float* Kb = Kg + (size_t)b * KSEQ * DIM;
  const unsigned int* VTb = (const unsigned int*)(VTg + (size_t)b * DIM * KSEQ);

  for (int tk = 0; tk < ntiles; tk++) {
    const int k0 = tk * 32;

    // ---- stage K-tile (fp32 -> bf16) ----
    {
      const int row = t >> 5, c4 = (t & 31) * 4;
#pragma unroll
      for (int p = 0; p < 4; p++) {
        const int r = row + p * 8;
        floatx4 f = *(const floatx4*)(Kb + (size_t)(k0 + r) * DIM + c4);
        shortx4 s4;
        s4[0] = (short)f2bf(f[0]); s4[1] = (short)f2bf(f[1]);
        s4[2] = (short)f2bf(f[2]); s4[3] = (short)f2bf(f[3]);
        *(shortx4*)&Kl[r][c4] = s4;
      }
      // ---- stage VT-tile (already bf16; dword copies) ----
      const int d = t >> 4, dwi = t & 15;
#pragma unroll
      for (int p = 0; p < 8; p++) {
        const int dd = d + p * 16;
        unsigned int w = VTb[(size_t)dd * (KSEQ / 2) + (k0 >> 1) + dwi];
        *((unsigned int*)&Vl[dd][0] + dwi) = w;
      }
    }
    __syncthreads();

    // ---- S = Q * K^T  (two 16-col halves) ----
    floatx4 s0 = (floatx4){0.f, 0.f, 0.f, 0.f};
    floatx4 s1 = (floatx4){0.f, 0.f, 0.f, 0.f};
#pragma unroll
    for (int c = 0; c < 4; c++) {
      short8 b0 = *(const short8*)&Kl[m][c * 32 + quad * 8];
      short8 b1 = *(const short8*)&Kl[16 + m][c * 32 + quad * 8];
      s0 = __builtin_amdgcn_mfma_f32_16x16x32_bf16(aq[c], b0, s0, 0, 0, 0);
      s1 = __builtin_amdgcn_mfma_f32_16x16x32_bf16(aq[c], b1, s1, 0, 0, 0);
    }

    // ---- scale + mask + online softmax ----
    const bool v0 = (k0 + m) < L, v1 = (k0 + 16 + m) < L;
    float p0[4], p1[4], mx[4];
#pragma unroll
    for (int r = 0; r < 4; r++) {
      p0[r] = v0 ? s0[r] * SCALE : -INFINITY;
      p1[r] = v1 ? s1[r] * SCALE : -INFINITY;
      mx[r] = fmaxf(p0[r], p1[r]);
    }
#pragma unroll
    for (int off = 1; off < 16; off <<= 1) {
#pragma unroll
      for (int r = 0; r < 4; r++) mx[r] = fmaxf(mx[r], __shfl_xor(mx[r], off));
    }
    float al[4], ts[4];
#pragma unroll
    for (int r = 0; r < 4; r++) {
      const float mn = fmaxf(mrow[r], mx[r]);
      al[r] = __expf(mrow[r] - mn);
      mrow[r] = mn;
      p0[r] = __expf(p0[r] - mn);
      p1[r] = __expf(p1[r] - mn);
      ts[r] = p0[r] + p1[r];
    }
#pragma unroll
    for (int off = 1; off < 16; off <<= 1) {
#pragma unroll
      for (int r = 0; r < 4; r++) ts[r] += __shfl_xor(ts[r], off);
    }
#pragma unroll
    for (int r = 0; r < 4; r++) lrow[r] = lrow[r] * al[r] + ts[r];
#pragma unroll
    for (int d = 0; d < 8; d++) {
#pragma unroll
      for (int r = 0; r < 4; r++) oacc[d][r] *= al[r];
    }

    // ---- P: C-layout -> A-layout via per-wave LDS round-trip ----
#pragma unroll
    for (int r = 0; r < 4; r++) {
      Pl[wave][quad * 4 + r][m]      = (short)f2bf(p0[r]);
      Pl[wave][quad * 4 + r][16 + m] = (short)f2bf(p1[r]);
    }
    // same-wave RAW: compiler inserts lgkmcnt wait; no barrier needed
    short8 pa = *(const short8*)&Pl[wave][m][quad * 8];

    // ---- O += P * V ----
#pragma unroll
    for (int d = 0; d < 8; d++) {
      short8 bv = *(const short8*)&Vl[d * 16 + m][quad * 8];
      oacc[d] = __builtin_amdgcn_mfma_f32_16x16x32_bf16(pa, bv, oacc[d], 0, 0, 0);
    }
    __syncthreads();   // protect Kl/Vl before next tile's staging
  }

  // ---- epilogue: normalize and store ----
  float inv[4];
#pragma unroll
  for (int r = 0; r < 4; r++) inv[r] = 1.0f / lrow[r];
  float* orow = Og + ((size_t)b * QLEN + qw) * DIM;
#pragma unroll
  for (int d = 0; d < 8; d++) {
#pragma unroll
    for (int r = 0; r < 4; r++)
      orow[(size_t)(quad * 4 + r) * DIM + d * 16 + m] = oacc[d][r] * inv[r];
  }
}

extern "C" void kernel_launch(void* const* d_in, const int* in_sizes, int n_in,
                              void* d_out, int out_size, void* d_ws, size_t ws_size,
                              hipStream_t stream) {
  const float* Qg = (const float*)d_in[0];
  const float* Kg = (const float*)d_in[1];
  const float* Vg = (const float*)d_in[2];
  const int*  vln = (const int*)d_in[3];
  unsigned short* VT = (unsigned short*)d_ws;   // needs B*D*K*2 = 8 MiB of scratch

  vt_kernel<<<dim3(DIM / 32, KSEQ / 32, B_), dim3(32, 8), 0, stream>>>(Vg, VT);
  attn_kernel<<<dim3(QLEN / 64, B_), dim3(256), 0, stream>>>(Qg, Kg, VT, vln,
                                                             (float*)d_out);
}

// Round 3
// 131.997 us; speedup vs baseline: 1.4994x; 1.4994x over previous
//
#include <hip/hip_runtime.h>
#include <hip/hip_bf16.h>
#include <stdint.h>

#define B_    32
#define QLEN  1024
#define KSEQ  1024
#define DIM   128
#define NKT   (KSEQ / 64)              // 16 key-tiles of 64 per batch
#define SCALE 0.08838834764831845f     // 1/sqrt(128)

typedef __attribute__((ext_vector_type(8))) short  short8;
typedef __attribute__((ext_vector_type(4))) float  floatx4;
typedef unsigned int u32;

__device__ __forceinline__ u32 f2bf(float x) {
  union { float f; u32 u; } v; v.f = x;
  return (v.u + 0x7FFF + ((v.u >> 16) & 1)) >> 16;   // RNE
}
__device__ __forceinline__ u32 pack2(float lo, float hi) {
  return f2bf(lo) | (f2bf(hi) << 16);
}

// Opaque full drain + barrier: forces vmcnt/lgkm drain and (via the "memory"
// clobber) forbids the compiler from moving global_load_lds across it.
__device__ __forceinline__ void barrier_full() {
  asm volatile("s_waitcnt vmcnt(0) lgkmcnt(0)" ::: "memory");
  __syncthreads();
}

// ---------------------------------------------------------------------------
// Prepass: build swizzled bf16 tile images in workspace.
//  K tiles:  [b][kt][row r=0..63][chunk c=0..15], chunk stored at c ^ (r&15)
//            chunk (r,c) = bf16 of K[b][kt*64+r][c*8 .. c*8+7]          (16B)
//  VT tiles: [b][kt][row d=0..127][chunk kc=0..7], chunk at kc ^ (d&7)
//            chunk (d,kc) = bf16 of V[b][kt*64+kc*8+j][d], j=0..7       (16B)
// Each tile image is 16 KiB and is DMA'd to LDS contiguously by attn_kernel.
// ---------------------------------------------------------------------------
__global__ __launch_bounds__(256) void prep_kernel(const float* __restrict__ Kg,
                                                   const float* __restrict__ Vg,
                                                   uint4* __restrict__ Ksw,
                                                   uint4* __restrict__ Vsw) {
  const int kt = blockIdx.x, b = blockIdx.y, t = threadIdx.x;
  if (blockIdx.z == 0) {
    const float* src = Kg + ((size_t)b * KSEQ + kt * 64) * DIM;
    uint4* dst = Ksw + ((size_t)b * NKT + kt) * 1024;
#pragma unroll
    for (int it = 0; it < 4; it++) {
      const int f = it * 256 + t, r = f >> 4, c = f & 15;
      floatx4 f0 = *(const floatx4*)(src + r * DIM + c * 8);
      floatx4 f1 = *(const floatx4*)(src + r * DIM + c * 8 + 4);
      uint4 o;
      o.x = pack2(f0[0], f0[1]); o.y = pack2(f0[2], f0[3]);
      o.z = pack2(f1[0], f1[1]); o.w = pack2(f1[2], f1[3]);
      dst[r * 16 + (c ^ (r & 15))] = o;
    }
  } else {
    __shared__ float Vt[64][132];
    const float* src = Vg + ((size_t)b * KSEQ + kt * 64) * DIM;
#pragma unroll
    for (int it = 0; it < 8; it++) {
      const int f = it * 256 + t, r = f >> 5, c4 = (f & 31) * 4;
      *(floatx4*)&Vt[r][c4] = *(const floatx4*)(src + r * DIM + c4);
    }
    __syncthreads();
    uint4* dst = Vsw + ((size_t)b * NKT + kt) * 1024;
#pragma unroll
    for (int it = 0; it < 4; it++) {
      const int g = it * 256 + t, d = g >> 3, kc = g & 7;
      uint4 o;
      o.x = pack2(Vt[kc * 8 + 0][d], Vt[kc * 8 + 1][d]);
      o.y = pack2(Vt[kc * 8 + 2][d], Vt[kc * 8 + 3][d]);
      o.z = pack2(Vt[kc * 8 + 4][d], Vt[kc * 8 + 5][d]);
      o.w = pack2(Vt[kc * 8 + 6][d], Vt[kc * 8 + 7][d]);
      dst[d * 8 + (kc ^ (d & 7))] = o;
    }
  }
}

// ---------------------------------------------------------------------------
// Main flash-attention kernel. block = 4 waves = 64 q rows; grid (16, 32).
// K: single 16KB buffer; V: double 16KB. All staging via global_load_lds
// dwordx4 of pre-swizzled tile images. Prefetch of tile tk+1 (both K and V)
// is issued ONLY after syncB(tk): in-flight window syncB(tk)->syncA(tk+1),
// during which the only LDS reads are Vbuf[tk&1] (disjoint) — race-free.
// ---------------------------------------------------------------------------
typedef const __attribute__((address_space(1))) u32* as1p;
typedef __attribute__((address_space(3))) u32* as3p;
__device__ __forceinline__ void gl_lds16(const void* g, void* l) {
  __builtin_amdgcn_global_load_lds((as1p)g, (as3p)l, 16, 0, 0);
}

__global__ __launch_bounds__(256, 2) void attn_kernel(
    const float* __restrict__ Qg, const uint4* __restrict__ Ksw,
    const uint4* __restrict__ Vsw, const int* __restrict__ vlen,
    float* __restrict__ Og) {
  __shared__ __align__(16) short Kbuf[64 * 128];        // 16 KB
  __shared__ __align__(16) short Vbuf[2][128 * 64];     // 32 KB
  __shared__ __align__(16) short Pl[4][16][72];         // per-wave P tile

  const int b = blockIdx.y, q0 = blockIdx.x * 64;
  const int t = threadIdx.x, wave = t >> 6, lane = t & 63;
  const int quad = lane >> 4, m = lane & 15;
  const int L  = vlen[b];
  const int nt = (L + 63) >> 6;

  const char* Kt = (const char*)(Ksw + (size_t)b * NKT * 1024);
  const char* Vt = (const char*)(Vsw + (size_t)b * NKT * 1024);

  // ---- Q fragments (A-layout), fp32 -> bf16 once ----
  short8 aq[4];
  {
    const float* qrow = Qg + ((size_t)b * QLEN + q0 + wave * 16 + m) * DIM;
#pragma unroll
    for (int c = 0; c < 4; c++) {
      floatx4 f0 = *(const floatx4*)(qrow + c * 32 + quad * 8);
      floatx4 f1 = *(const floatx4*)(qrow + c * 32 + quad * 8 + 4);
      short8 a;
      a[0] = (short)f2bf(f0[0]); a[1] = (short)f2bf(f0[1]);
      a[2] = (short)f2bf(f0[2]); a[3] = (short)f2bf(f0[3]);
      a[4] = (short)f2bf(f1[0]); a[5] = (short)f2bf(f1[1]);
      a[6] = (short)f2bf(f1[2]); a[7] = (short)f2bf(f1[3]);
      aq[c] = a;
    }
  }

  float mrow[4], lrow[4];
  floatx4 oacc[8];
#pragma unroll
  for (int r = 0; r < 4; r++) { mrow[r] = -INFINITY; lrow[r] = 0.0f; }
#pragma unroll
  for (int d = 0; d < 8; d++) oacc[d] = (floatx4){0.f, 0.f, 0.f, 0.f};

  // per-wave DMA slices: wave w stages bytes [w*4096, w*4096+4096) of each tile
#define ISSUE_K(tk)                                                          \
  {                                                                          \
    const char* g_ = Kt + (size_t)(tk) * 16384 + wave * 4096 + lane * 16;    \
    _Pragma("unroll") for (int i_ = 0; i_ < 4; i_++)                         \
        gl_lds16(g_ + i_ * 1024, (char*)Kbuf + wave * 4096 + i_ * 1024);     \
  }
#define ISSUE_V(tk, bb)                                                      \
  {                                                                          \
    const char* g_ = Vt + (size_t)(tk) * 16384 + wave * 4096 + lane * 16;    \
    _Pragma("unroll") for (int i_ = 0; i_ < 4; i_++)                         \
        gl_lds16(g_ + i_ * 1024, (char*)Vbuf[bb] + wave * 4096 + i_ * 1024); \
  }

  ISSUE_K(0);
  ISSUE_V(0, 0);

  for (int tk = 0; tk < nt; tk++) {
    const int k0 = tk * 64;
    barrier_full();                        // syncA: K(tk) + V(tk) landed

    // ---- S = Q K^T : 4 subtiles of 16 keys ----
    floatx4 sa[4];
#pragma unroll
    for (int s = 0; s < 4; s++) sa[s] = (floatx4){0.f, 0.f, 0.f, 0.f};
#pragma unroll
    for (int s = 0; s < 4; s++) {
#pragma unroll
      for (int c = 0; c < 4; c++) {
        const short8 bk = *(const short8*)(Kbuf + (s * 16 + m) * 128 +
                                           (((c * 4 + quad) ^ m) & 15) * 8);
        sa[s] = __builtin_amdgcn_mfma_f32_16x16x32_bf16(aq[c], bk, sa[s], 0, 0, 0);
      }
    }

    // ---- mask + online softmax ----
    float p[4][4], mx[4];
    const bool vv0 = (k0 + m) < L,      vv1 = (k0 + 16 + m) < L;
    const bool vv2 = (k0 + 32 + m) < L, vv3 = (k0 + 48 + m) < L;
#pragma unroll
    for (int r = 0; r < 4; r++) {
      p[0][r] = vv0 ? sa[0][r] * SCALE : -INFINITY;
      p[1][r] = vv1 ? sa[1][r] * SCALE : -INFINITY;
      p[2][r] = vv2 ? sa[2][r] * SCALE : -INFINITY;
      p[3][r] = vv3 ? sa[3][r] * SCALE : -INFINITY;
      mx[r] = fmaxf(fmaxf(p[0][r], p[1][r]), fmaxf(p[2][r], p[3][r]));
    }
#pragma unroll
    for (int off = 1; off < 16; off <<= 1) {
#pragma unroll
      for (int r = 0; r < 4; r++) mx[r] = fmaxf(mx[r], __shfl_xor(mx[r], off));
    }
    float al[4], ts[4];
#pragma unroll
    for (int r = 0; r < 4; r++) {
      const float mn = fmaxf(mrow[r], mx[r]);
      al[r] = __expf(mrow[r] - mn);
      mrow[r] = mn;
#pragma unroll
      for (int s = 0; s < 4; s++) p[s][r] = __expf(p[s][r] - mn);
      ts[r] = (p[0][r] + p[1][r]) + (p[2][r] + p[3][r]);
    }
#pragma unroll
    for (int off = 1; off < 16; off <<= 1) {
#pragma unroll
      for (int r = 0; r < 4; r++) ts[r] += __shfl_xor(ts[r], off);
    }
#pragma unroll
    for (int r = 0; r < 4; r++) lrow[r] = lrow[r] * al[r] + ts[r];
#pragma unroll
    for (int d = 0; d < 8; d++) {
#pragma unroll
      for (int r = 0; r < 4; r++) oacc[d][r] *= al[r];
    }

    // ---- P: C-layout -> A-layout via per-wave LDS round-trip ----
#pragma unroll
    for (int s = 0; s < 4; s++) {
#pragma unroll
      for (int r = 0; r < 4; r++)
        Pl[wave][quad * 4 + r][s * 16 + m] = (short)f2bf(p[s][r]);
    }
    asm volatile("s_waitcnt lgkmcnt(0)" ::: "memory");   // same-wave RAW fence
    const short8 pa0 = *(const short8*)&Pl[wave][m][quad * 8];
    const short8 pa1 = *(const short8*)&Pl[wave][m][32 + quad * 8];

    barrier_full();                        // syncB: all waves done with Kbuf/Pl
    if (tk + 1 < nt) {                     // prefetch both tiles; only reader
      ISSUE_K(tk + 1);                     // of LDS until next syncA is
      ISSUE_V(tk + 1, (tk + 1) & 1);       // Vbuf[tk&1] (disjoint buffer)
    }

    // ---- O += P V  (VT tile: row = output dim, swizzled key-chunks) ----
    const short* Vb_ = Vbuf[tk & 1];
#pragma unroll
    for (int d = 0; d < 8; d++) {
      const int row = d * 16 + m;
      const short8 bv0 = *(const short8*)(Vb_ + row * 64 + ((quad ^ (m & 7)) & 7) * 8);
      const short8 bv1 = *(const short8*)(Vb_ + row * 64 + (((quad + 4) ^ (m & 7)) & 7) * 8);
      oacc[d] = __builtin_amdgcn_mfma_f32_16x16x32_bf16(pa0, bv0, oacc[d], 0, 0, 0);
      oacc[d] = __builtin_amdgcn_mfma_f32_16x16x32_bf16(pa1, bv1, oacc[d], 0, 0, 0);
    }
  }

  // ---- epilogue ----
  float inv[4];
#pragma unroll
  for (int r = 0; r < 4; r++) inv[r] = 1.0f / lrow[r];
  float* orow = Og + ((size_t)b * QLEN + q0 + wave * 16) * DIM;
#pragma unroll
  for (int d = 0; d < 8; d++) {
#pragma unroll
    for (int r = 0; r < 4; r++)
      orow[(size_t)(quad * 4 + r) * DIM + d * 16 + m] = oacc[d][r] * inv[r];
  }
#undef ISSUE_K
#undef ISSUE_V
}

extern "C" void kernel_launch(void* const* d_in, const int* in_sizes, int n_in,
                              void* d_out, int out_size, void* d_ws, size_t ws_size,
                              hipStream_t stream) {
  const float* Qg = (const float*)d_in[0];
  const float* Kg = (const float*)d_in[1];
  const float* Vg = (const float*)d_in[2];
  const int*  vln = (const int*)d_in[3];
  uint4* Ksw = (uint4*)d_ws;                                      // 8 MiB
  uint4* Vsw = (uint4*)((char*)d_ws + (size_t)B_ * NKT * 16384);  // 8 MiB

  prep_kernel<<<dim3(NKT, B_, 2), 256, 0, stream>>>(Kg, Vg, Ksw, Vsw);
  attn_kernel<<<dim3(QLEN / 64, B_), 256, 0, stream>>>(Qg, Ksw, Vsw, vln,
                                                       (float*)d_out);
}

// Round 4
// 128.820 us; speedup vs baseline: 1.5364x; 1.0247x over previous
//
#include <hip/hip_runtime.h>
#include <hip/hip_bf16.h>
#include <stdint.h>

#define B_    32
#define QLEN  1024
#define KSEQ  1024
#define DIM   128
#define NKT   (KSEQ / 64)              // 16 key-tiles of 64 per batch
#define SCALE 0.08838834764831845f     // 1/sqrt(128)

typedef __attribute__((ext_vector_type(8))) short  short8;
typedef __attribute__((ext_vector_type(4))) float  floatx4;
typedef unsigned int u32;

__device__ __forceinline__ u32 f2bf(float x) {
  union { float f; u32 u; } v; v.f = x;
  return (v.u + 0x7FFF + ((v.u >> 16) & 1)) >> 16;   // RNE
}
__device__ __forceinline__ u32 pack2(float lo, float hi) {
  return f2bf(lo) | (f2bf(hi) << 16);
}

// Opaque full drain + barrier: forces vmcnt/lgkm drain and (via the "memory"
// clobber) forbids the compiler from moving global_load_lds across it.
__device__ __forceinline__ void barrier_full() {
  asm volatile("s_waitcnt vmcnt(0) lgkmcnt(0)" ::: "memory");
  __syncthreads();
}

// ---------------------------------------------------------------------------
// Prepass: build swizzled bf16 tile images in workspace (skips tiles beyond
// each batch's valid_length — attn never reads those).
//  K tiles:  [b][kt][row r=0..63][chunk c=0..15], chunk stored at c ^ (r&15)
//  VT tiles: [b][kt][row d=0..127][chunk kc=0..7], chunk at kc ^ (d&7)
// ---------------------------------------------------------------------------
__global__ __launch_bounds__(256) void prep_kernel(const float* __restrict__ Kg,
                                                   const float* __restrict__ Vg,
                                                   const int* __restrict__ vlen,
                                                   uint4* __restrict__ Ksw,
                                                   uint4* __restrict__ Vsw) {
  const int kt = blockIdx.x, b = blockIdx.y, t = threadIdx.x;
  if (kt * 64 >= vlen[b]) return;        // tile never used
  if (blockIdx.z == 0) {
    const float* src = Kg + ((size_t)b * KSEQ + kt * 64) * DIM;
    uint4* dst = Ksw + ((size_t)b * NKT + kt) * 1024;
#pragma unroll
    for (int it = 0; it < 4; it++) {
      const int f = it * 256 + t, r = f >> 4, c = f & 15;
      floatx4 f0 = *(const floatx4*)(src + r * DIM + c * 8);
      floatx4 f1 = *(const floatx4*)(src + r * DIM + c * 8 + 4);
      uint4 o;
      o.x = pack2(f0[0], f0[1]); o.y = pack2(f0[2], f0[3]);
      o.z = pack2(f1[0], f1[1]); o.w = pack2(f1[2], f1[3]);
      dst[r * 16 + (c ^ (r & 15))] = o;
    }
  } else {
    __shared__ float Vt[64][132];
    const float* src = Vg + ((size_t)b * KSEQ + kt * 64) * DIM;
#pragma unroll
    for (int it = 0; it < 8; it++) {
      const int f = it * 256 + t, r = f >> 5, c4 = (f & 31) * 4;
      *(floatx4*)&Vt[r][c4] = *(const floatx4*)(src + r * DIM + c4);
    }
    __syncthreads();
    uint4* dst = Vsw + ((size_t)b * NKT + kt) * 1024;
#pragma unroll
    for (int it = 0; it < 4; it++) {
      const int g = it * 256 + t, d = g >> 3, kc = g & 7;
      uint4 o;
      o.x = pack2(Vt[kc * 8 + 0][d], Vt[kc * 8 + 1][d]);
      o.y = pack2(Vt[kc * 8 + 2][d], Vt[kc * 8 + 3][d]);
      o.z = pack2(Vt[kc * 8 + 4][d], Vt[kc * 8 + 5][d]);
      o.w = pack2(Vt[kc * 8 + 6][d], Vt[kc * 8 + 7][d]);
      dst[d * 8 + (kc ^ (d & 7))] = o;
    }
  }
}

// ---------------------------------------------------------------------------
// Main flash-attention kernel. block = 4 waves = 64 q rows; grid (16, 32).
// BOTH K and V double-buffered; ONE barrier per iteration. Prefetch of tile
// tk+1 is issued immediately after the barrier, giving it the whole
// iteration (QK + softmax + PV) to land. Race audit: DMA(tk+1) writes
// buf[(tk+1)&1]; all waves in iter tk have passed barrier(tk), hence are
// done reading buf[(tk-1)&1] == buf[(tk+1)&1]. Compute(tk) reads buf[tk&1],
// disjoint from the in-flight DMA.
// ---------------------------------------------------------------------------
typedef const __attribute__((address_space(1))) u32* as1p;
typedef __attribute__((address_space(3))) u32* as3p;
__device__ __forceinline__ void gl_lds16(const void* g, void* l) {
  __builtin_amdgcn_global_load_lds((as1p)g, (as3p)l, 16, 0, 0);
}

__global__ __launch_bounds__(256, 2) void attn_kernel(
    const float* __restrict__ Qg, const uint4* __restrict__ Ksw,
    const uint4* __restrict__ Vsw, const int* __restrict__ vlen,
    float* __restrict__ Og) {
  __shared__ __align__(16) short Kbuf[2][64 * 128];     // 32 KB
  __shared__ __align__(16) short Vbuf[2][128 * 64];     // 32 KB
  __shared__ __align__(16) short Pl[4][16][72];         // per-wave P tile

  const int b = blockIdx.y, q0 = blockIdx.x * 64;
  const int t = threadIdx.x, wave = t >> 6, lane = t & 63;
  const int quad = lane >> 4, m = lane & 15;
  const int L  = vlen[b];
  const int nt = (L + 63) >> 6;

  const char* Kt = (const char*)(Ksw + (size_t)b * NKT * 1024);
  const char* Vt = (const char*)(Vsw + (size_t)b * NKT * 1024);

  // ---- Q fragments (A-layout), fp32 -> bf16 once ----
  short8 aq[4];
  {
    const float* qrow = Qg + ((size_t)b * QLEN + q0 + wave * 16 + m) * DIM;
#pragma unroll
    for (int c = 0; c < 4; c++) {
      floatx4 f0 = *(const floatx4*)(qrow + c * 32 + quad * 8);
      floatx4 f1 = *(const floatx4*)(qrow + c * 32 + quad * 8 + 4);
      short8 a;
      a[0] = (short)f2bf(f0[0]); a[1] = (short)f2bf(f0[1]);
      a[2] = (short)f2bf(f0[2]); a[3] = (short)f2bf(f0[3]);
      a[4] = (short)f2bf(f1[0]); a[5] = (short)f2bf(f1[1]);
      a[6] = (short)f2bf(f1[2]); a[7] = (short)f2bf(f1[3]);
      aq[c] = a;
    }
  }

  float mrow[4], lrow[4];
  floatx4 oacc[8];
#pragma unroll
  for (int r = 0; r < 4; r++) { mrow[r] = -INFINITY; lrow[r] = 0.0f; }
#pragma unroll
  for (int d = 0; d < 8; d++) oacc[d] = (floatx4){0.f, 0.f, 0.f, 0.f};

  // per-wave DMA slices: wave w stages bytes [w*4096, w*4096+4096) of each tile
#define ISSUE_K(tk, bb)                                                        \
  {                                                                            \
    const char* g_ = Kt + (size_t)(tk) * 16384 + wave * 4096 + lane * 16;      \
    _Pragma("unroll") for (int i_ = 0; i_ < 4; i_++)                           \
        gl_lds16(g_ + i_ * 1024, (char*)Kbuf[bb] + wave * 4096 + i_ * 1024);   \
  }
#define ISSUE_V(tk, bb)                                                        \
  {                                                                            \
    const char* g_ = Vt + (size_t)(tk) * 16384 + wave * 4096 + lane * 16;      \
    _Pragma("unroll") for (int i_ = 0; i_ < 4; i_++)                           \
        gl_lds16(g_ + i_ * 1024, (char*)Vbuf[bb] + wave * 4096 + i_ * 1024);   \
  }

  ISSUE_K(0, 0);
  ISSUE_V(0, 0);

  for (int tk = 0; tk < nt; tk++) {
    const int k0 = tk * 64;
    barrier_full();                        // DMA(tk) landed; buf[(tk+1)&1] free
    if (tk + 1 < nt) {                     // prefetch next tile: whole iter to land
      ISSUE_K(tk + 1, (tk + 1) & 1);
      ISSUE_V(tk + 1, (tk + 1) & 1);
    }
    const short* Kb_ = Kbuf[tk & 1];
    const short* Vb_ = Vbuf[tk & 1];

    // ---- S = Q K^T : 4 subtiles of 16 keys ----
    floatx4 sa[4];
#pragma unroll
    for (int s = 0; s < 4; s++) sa[s] = (floatx4){0.f, 0.f, 0.f, 0.f};
#pragma unroll
    for (int s = 0; s < 4; s++) {
#pragma unroll
      for (int c = 0; c < 4; c++) {
        const short8 bk = *(const short8*)(Kb_ + (s * 16 + m) * 128 +
                                           (((c * 4 + quad) ^ m) & 15) * 8);
        sa[s] = __builtin_amdgcn_mfma_f32_16x16x32_bf16(aq[c], bk, sa[s], 0, 0, 0);
      }
    }

    // ---- mask + online softmax (wave-uniform fast path when fully valid) ----
    float p[4][4], mx[4];
    if (k0 + 64 <= L) {
#pragma unroll
      for (int r = 0; r < 4; r++) {
#pragma unroll
        for (int s = 0; s < 4; s++) p[s][r] = sa[s][r] * SCALE;
        mx[r] = fmaxf(fmaxf(p[0][r], p[1][r]), fmaxf(p[2][r], p[3][r]));
      }
    } else {
      const bool vv0 = (k0 + m) < L,      vv1 = (k0 + 16 + m) < L;
      const bool vv2 = (k0 + 32 + m) < L, vv3 = (k0 + 48 + m) < L;
#pragma unroll
      for (int r = 0; r < 4; r++) {
        p[0][r] = vv0 ? sa[0][r] * SCALE : -INFINITY;
        p[1][r] = vv1 ? sa[1][r] * SCALE : -INFINITY;
        p[2][r] = vv2 ? sa[2][r] * SCALE : -INFINITY;
        p[3][r] = vv3 ? sa[3][r] * SCALE : -INFINITY;
        mx[r] = fmaxf(fmaxf(p[0][r], p[1][r]), fmaxf(p[2][r], p[3][r]));
      }
    }
#pragma unroll
    for (int off = 1; off < 16; off <<= 1) {
#pragma unroll
      for (int r = 0; r < 4; r++) mx[r] = fmaxf(mx[r], __shfl_xor(mx[r], off));
    }
    float al[4], ts[4];
#pragma unroll
    for (int r = 0; r < 4; r++) {
      const float mn = fmaxf(mrow[r], mx[r]);
      al[r] = __expf(mrow[r] - mn);
      mrow[r] = mn;
#pragma unroll
      for (int s = 0; s < 4; s++) p[s][r] = __expf(p[s][r] - mn);
      ts[r] = (p[0][r] + p[1][r]) + (p[2][r] + p[3][r]);
    }
#pragma unroll
    for (int off = 1; off < 16; off <<= 1) {
#pragma unroll
      for (int r = 0; r < 4; r++) ts[r] += __shfl_xor(ts[r], off);
    }
#pragma unroll
    for (int r = 0; r < 4; r++) lrow[r] = lrow[r] * al[r] + ts[r];
#pragma unroll
    for (int d = 0; d < 8; d++) {
#pragma unroll
      for (int r = 0; r < 4; r++) oacc[d][r] *= al[r];
    }

    // ---- P: C-layout -> A-layout via per-wave LDS round-trip ----
#pragma unroll
    for (int s = 0; s < 4; s++) {
#pragma unroll
      for (int r = 0; r < 4; r++)
        Pl[wave][quad * 4 + r][s * 16 + m] = (short)f2bf(p[s][r]);
    }
    asm volatile("s_waitcnt lgkmcnt(0)" ::: "memory");   // same-wave RAW fence
    const short8 pa0 = *(const short8*)&Pl[wave][m][quad * 8];
    const short8 pa1 = *(const short8*)&Pl[wave][m][32 + quad * 8];

    // ---- O += P V  (VT tile: row = output dim, swizzled key-chunks) ----
#pragma unroll
    for (int d = 0; d < 8; d++) {
      const int row = d * 16 + m;
      const short8 bv0 = *(const short8*)(Vb_ + row * 64 + ((quad ^ (m & 7)) & 7) * 8);
      const short8 bv1 = *(const short8*)(Vb_ + row * 64 + (((quad + 4) ^ (m & 7)) & 7) * 8);
      oacc[d] = __builtin_amdgcn_mfma_f32_16x16x32_bf16(pa0, bv0, oacc[d], 0, 0, 0);
      oacc[d] = __builtin_amdgcn_mfma_f32_16x16x32_bf16(pa1, bv1, oacc[d], 0, 0, 0);
    }
  }

  // ---- epilogue ----
  float inv[4];
#pragma unroll
  for (int r = 0; r < 4; r++) inv[r] = 1.0f / lrow[r];
  float* orow = Og + ((size_t)b * QLEN + q0 + wave * 16) * DIM;
#pragma unroll
  for (int d = 0; d < 8; d++) {
#pragma unroll
    for (int r = 0; r < 4; r++)
      orow[(size_t)(quad * 4 + r) * DIM + d * 16 + m] = oacc[d][r] * inv[r];
  }
#undef ISSUE_K
#undef ISSUE_V
}

extern "C" void kernel_launch(void* const* d_in, const int* in_sizes, int n_in,
                              void* d_out, int out_size, void* d_ws, size_t ws_size,
                              hipStream_t stream) {
  const float* Qg = (const float*)d_in[0];
  const float* Kg = (const float*)d_in[1];
  const float* Vg = (const float*)d_in[2];
  const int*  vln = (const int*)d_in[3];
  uint4* Ksw = (uint4*)d_ws;                                      // 8 MiB
  uint4* Vsw = (uint4*)((char*)d_ws + (size_t)B_ * NKT * 16384);  // 8 MiB

  prep_kernel<<<dim3(NKT, B_, 2), 256, 0, stream>>>(Kg, Vg, vln, Ksw, Vsw);
  attn_kernel<<<dim3(QLEN / 64, B_), 256, 0, stream>>>(Qg, Ksw, Vsw, vln,
                                                       (float*)d_out);
}